// Round 5
// baseline (492.207 us; speedup 1.0000x reference)
//
#include <hip/hip_runtime.h>
#include <stdint.h>

// Problem constants
#define SEQ   2048
#define NHEAD 16
#define DHEAD 64
#define NROWS 4096      // BSZ*SEQ
#define MDIM  2048      // model dim
#define QKVN  6144
#define EPSF  1e-5f
#define LAMBDA_INIT 0.7999593627581f
#define QSCALE 0.18033688011112042f   // dh^-0.5 * log2(e): flash softmax runs in exp2 domain

typedef unsigned short u16;
typedef __attribute__((ext_vector_type(8))) short bf16x8;   // 8 bf16 = 4 VGPRs
typedef __attribute__((ext_vector_type(4))) float f32x4;
typedef __attribute__((ext_vector_type(4))) unsigned short u16x4;

// async global->LDS, 16B/lane: data lands at LDS base + lane*16 (wave-uniform base).
#define GLD_LDS16(g, l) \
  __builtin_amdgcn_global_load_lds((const __attribute__((address_space(1))) void*)(g), \
                                   (__attribute__((address_space(3))) void*)(l), 16, 0, 0)

__device__ __forceinline__ u16 f2bf(float f) {
  union { float f; uint32_t u; } v; v.f = f;
  return (u16)((v.u + 0x7fffu + ((v.u >> 16) & 1u)) >> 16);   // RNE
}
__device__ __forceinline__ float bf2f(uint32_t s) {
  union { uint32_t u; float f; } v; v.u = s << 16; return v.f;
}

// ---------------- cast fp32 -> bf16 (vectorized) ----------------
__global__ __launch_bounds__(256) void k_cast(const float4* __restrict__ src,
                                              u16* __restrict__ dst, int n4) {
  int i = blockIdx.x * 256 + threadIdx.x;
  if (i < n4) {
    float4 f = src[i];
    u16x4 o;
    o.x = f2bf(f.x); o.y = f2bf(f.y); o.z = f2bf(f.z); o.w = f2bf(f.w);
    *(u16x4*)(dst + (size_t)i * 4) = o;
  }
}
// 4 equal-size weight casts in one launch (blockIdx.y selects tensor)
__global__ __launch_bounds__(256) void k_castw(const float4* __restrict__ s0,
                                               const float4* __restrict__ s1,
                                               const float4* __restrict__ s2,
                                               const float4* __restrict__ s3,
                                               u16* __restrict__ d0, u16* __restrict__ d1,
                                               u16* __restrict__ d2, u16* __restrict__ d3) {
  int i = blockIdx.x * 256 + threadIdx.x;
  const float4* s = blockIdx.y == 0 ? s0 : blockIdx.y == 1 ? s1 : blockIdx.y == 2 ? s2 : s3;
  u16* d = blockIdx.y == 0 ? d0 : blockIdx.y == 1 ? d1 : blockIdx.y == 2 ? d2 : d3;
  float4 f = s[i];
  u16x4 o;
  o.x = f2bf(f.x); o.y = f2bf(f.y); o.z = f2bf(f.z); o.w = f2bf(f.w);
  *(u16x4*)(d + (size_t)i * 4) = o;
}

// ---------------- BT-GEMM: C(MxN) = A(MxK) @ B(NxK)^T, bf16 in, fp32/bf16 out ----
template<int BF16OUT>
__global__ __launch_bounds__(256) void k_gemm_bt(const u16* __restrict__ A,
                                                 const u16* __restrict__ B,
                                                 void* __restrict__ Cp,
                                                 int M, int N, int K) {
  __shared__ __align__(16) u16 As[128 * 64];
  __shared__ __align__(16) u16 Bs[128 * 64];
  const int t = threadIdx.x, w = t >> 6, l = t & 63, n = l & 15, g = l >> 4;
  const int m0 = blockIdx.y * 128, n0 = blockIdx.x * 128;
  const int wm = (w >> 1) * 64, wn = (w & 1) * 64;
  f32x4 acc[4][4];
  #pragma unroll
  for (int i = 0; i < 4; i++)
    #pragma unroll
    for (int j = 0; j < 4; j++) acc[i][j] = (f32x4){0.f, 0.f, 0.f, 0.f};

  for (int kt = 0; kt < K; kt += 64) {
    #pragma unroll
    for (int p = 0; p < 4; ++p) {
      int id = p * 256 + t;
      int row = id >> 3, cc = id & 7, ccg = (cc ^ row) & 7;
      GLD_LDS16(A + (size_t)(m0 + row) * K + kt + ccg * 8, As + (size_t)(p * 256 + w * 64) * 8);
      GLD_LDS16(B + (size_t)(n0 + row) * K + kt + ccg * 8, Bs + (size_t)(p * 256 + w * 64) * 8);
    }
    __syncthreads();
    bf16x8 af[4][2], bfr[4][2];
    #pragma unroll
    for (int mi = 0; mi < 4; mi++) {
      int row = wm + mi * 16 + n;
      #pragma unroll
      for (int c = 0; c < 2; c++)
        af[mi][c] = *(const bf16x8*)(As + ((size_t)row * 8 + (((c * 4 + g) ^ row) & 7)) * 8);
    }
    #pragma unroll
    for (int ni = 0; ni < 4; ni++) {
      int row = wn + ni * 16 + n;
      #pragma unroll
      for (int c = 0; c < 2; c++)
        bfr[ni][c] = *(const bf16x8*)(Bs + ((size_t)row * 8 + (((c * 4 + g) ^ row) & 7)) * 8);
    }
    #pragma unroll
    for (int mi = 0; mi < 4; mi++)
      #pragma unroll
      for (int ni = 0; ni < 4; ni++)
        #pragma unroll
        for (int c = 0; c < 2; c++)
          acc[mi][ni] = __builtin_amdgcn_mfma_f32_16x16x32_bf16(af[mi][c], bfr[ni][c], acc[mi][ni], 0, 0, 0);
    __syncthreads();
  }
  #pragma unroll
  for (int mi = 0; mi < 4; mi++)
    #pragma unroll
    for (int ni = 0; ni < 4; ni++)
      #pragma unroll
      for (int r = 0; r < 4; r++) {
        int row = m0 + wm + mi * 16 + g * 4 + r;
        int col = n0 + wn + ni * 16 + n;
        if (BF16OUT) ((u16*)Cp)[(size_t)row * N + col] = f2bf(acc[mi][ni][r]);
        else         ((float*)Cp)[(size_t)row * N + col] = acc[mi][ni][r];
      }
}

// ---------------- RoPE + repack Q,K into per-instance layout ----------------
__global__ __launch_bounds__(256) void k_rope(const u16* __restrict__ QKV,
                                              const float* __restrict__ cosb,
                                              const float* __restrict__ sinb,
                                              u16* __restrict__ Qo, u16* __restrict__ Ko) {
  int tid = blockIdx.x * 256 + threadIdx.x;     // 2 * 4096 * 1024 = 2^23 threads
  int tensor = tid >> 22;
  int rem = tid & ((1 << 22) - 1);
  int r = rem >> 10;
  int p = rem & 1023;
  int rh = p >> 5, i = p & 31;
  int s = r & (SEQ - 1);
  int col = tensor * 2048 + rh * 64 + 2 * i;
  uint32_t u = *(const uint32_t*)(QKV + (size_t)r * QKVN + col);
  float a = bf2f(u & 0xffffu), bb = bf2f(u >> 16);
  float c = cosb[s * 32 + i], sn = sinb[s * 32 + i];
  float o0 = a * c - bb * sn;
  float o1 = a * sn + bb * c;
  if (tensor == 0) { o0 *= QSCALE; o1 *= QSCALE; }
  int inst = (r >> 11) * 32 + rh;
  u16* dst = (tensor ? Ko : Qo) + ((size_t)inst * SEQ + s) * 64 + 2 * i;
  *(uint32_t*)dst = (uint32_t)f2bf(o0) | ((uint32_t)f2bf(o1) << 16);
}

// ---------------- V transpose: QKV V-cols -> Vt TILED [bh][kt=32][128 dv][64 key]
__global__ __launch_bounds__(256) void k_vtrans(const u16* __restrict__ QKV,
                                                u16* __restrict__ Vt) {
  __shared__ __align__(16) u16 tile[64 * 80];   // pad to 160B stride
  int t = threadIdx.x;
  int st = blockIdx.x, dt = blockIdx.y, bh = blockIdx.z;
  int b = bh >> 4, h = bh & 15;
  #pragma unroll
  for (int p = 0; p < 2; p++) {
    int id = p * 256 + t, sr = id >> 3, cc = id & 7;
    const u16* gsrc = QKV + (size_t)(b * SEQ + st * 64 + sr) * QKVN + 4096 + h * 128 + dt * 64 + cc * 8;
    *(uint4*)(tile + sr * 80 + cc * 8) = *(const uint4*)gsrc;
  }
  __syncthreads();
  #pragma unroll
  for (int p = 0; p < 2; p++) {
    int id = p * 256 + t, dr = id >> 3, cc = id & 7;
    union { u16 v[8]; uint4 q; } uu;
    #pragma unroll
    for (int j = 0; j < 8; j++) uu.v[j] = tile[(cc * 8 + j) * 80 + dr];
    u16* gdst = Vt + (((size_t)bh * 32 + st) * 128 + dt * 64 + dr) * 64 + cc * 8;
    *(uint4*)gdst = uu.q;
  }
}

// ---------------- lambda scalar ----------------
__global__ __launch_bounds__(64) void k_lambda(const float* lq1, const float* lk1,
                                               const float* lq2, const float* lk2,
                                               float* out) {
  int l = threadIdx.x;
  float s1 = lq1[l] * lk1[l];
  float s2 = lq2[l] * lk2[l];
  #pragma unroll
  for (int d = 1; d < 64; d <<= 1) { s1 += __shfl_xor(s1, d); s2 += __shfl_xor(s2, d); }
  if (l == 0) *out = expf(s1) - expf(s2) + LAMBDA_INIT;
}

// ---------------- flash attention v5 (causal), dqk=64, dv=128 ----------------
// v4 structure (single barrier/k-tile, dbuf staging, S^T per-lane softmax)
// with M=32 q-rows/wave (two 16-row sub-blocks): kf/vf fragments read ONCE,
// fed to TWO MFMAs -> LDS-read traffic per FLOP nearly halves (the v4
// bottleneck: ~26 b128 reads / 24 MFMAs -> now 28 / 48).
// 256-thread blocks (4 waves), q-tile 128, grid 1024 (same backfill as v4).
// LDS 66KB -> 2 blocks/CU (8 waves/CU). P rows padded to 72 u16 (144B) to
// kill the v4 bank conflicts (128B rows = exact 32-bank wrap).
// Fully-masked sub-blocks computed anyway: exp2(-1e30)=0 -> exact zero
// contribution, keeps control flow wave-uniform.
__global__ __launch_bounds__(256, 2) void k_flash(const u16* __restrict__ Q,
                                                  const u16* __restrict__ K,
                                                  const u16* __restrict__ V,
                                                  u16* __restrict__ O) {
  __shared__ __align__(16) u16 Ks[2][64 * 64];
  __shared__ __align__(16) u16 Vs[2][128 * 64];
  __shared__ __align__(16) u16 Ps[4][32 * 72];
  const int t = threadIdx.x, w = t >> 6, l = t & 63, n = l & 15, g = l >> 4;
  const int gb = blockIdx.x;
  const int rem = gb & 127, xcd = rem & 7, ps = rem >> 3;
  const int inst = (gb >> 7) * 8 + xcd;
  const int qb = (15 - ps) * 128;             // longest q-tiles first
  const int b = inst >> 5, rh = inst & 31, h = rh >> 1, bh = b * 16 + h;
  const u16* Qp = Q + (size_t)inst * SEQ * 64;
  const u16* Kp = K + (size_t)inst * SEQ * 64;
  const u16* Vp = V + (size_t)bh * 32 * 128 * 64;   // tiled [kt][dv][key]
  u16* Pw = Ps[w];
  const int rw = qb + w * 32;                 // this wave's 32 q-rows

  bf16x8 qf[2][2];
  #pragma unroll
  for (int q2 = 0; q2 < 2; q2++)
    #pragma unroll
    for (int c = 0; c < 2; c++)
      qf[q2][c] = *(const bf16x8*)(Qp + (size_t)(rw + q2 * 16 + n) * 64 + c * 32 + g * 8);

  f32x4 o_acc[2][8];
  #pragma unroll
  for (int q2 = 0; q2 < 2; q2++)
    #pragma unroll
    for (int nb = 0; nb < 8; nb++) o_acc[q2][nb] = (f32x4){0.f, 0.f, 0.f, 0.f};
  float lsum[2] = {0.f, 0.f};                 // per-lane partial row sums

  const int nkt = (qb >> 6) + 2;

  // ---- stage tile 0 into buffer 0 ----
  #pragma unroll
  for (int p = 0; p < 2; p++) {
    int id = p * 256 + t, row = id >> 3, cc = id & 7, ccg = (cc ^ row) & 7;
    GLD_LDS16(Kp + (size_t)row * 64 + ccg * 8, Ks[0] + (size_t)(p * 256 + w * 64) * 8);
  }
  #pragma unroll
  for (int p = 0; p < 4; p++) {
    int id = p * 256 + t, vr = id >> 3, vc = id & 7, vcg = (vc ^ vr) & 7;
    GLD_LDS16(Vp + (size_t)vr * 64 + vcg * 8, Vs[0] + (size_t)(p * 256 + w * 64) * 8);
  }

  for (int kt = 0; kt < nkt; ++kt) {
    __syncthreads();                          // drains stage(kt); frees buf[(kt+1)&1]
    if (kt + 1 < nkt) {                       // prefetch kt+1 (in flight during compute)
      #pragma unroll
      for (int p = 0; p < 2; p++) {
        int id = p * 256 + t, row = id >> 3, cc = id & 7, ccg = (cc ^ row) & 7;
        GLD_LDS16(Kp + (size_t)((kt + 1) * 64 + row) * 64 + ccg * 8,
                  Ks[(kt + 1) & 1] + (size_t)(p * 256 + w * 64) * 8);
      }
      const u16* Vtile = Vp + (size_t)(kt + 1) * (128 * 64);
      #pragma unroll
      for (int p = 0; p < 4; p++) {
        int id = p * 256 + t, vr = id >> 3, vc = id & 7, vcg = (vc ^ vr) & 7;
        GLD_LDS16(Vtile + (size_t)vr * 64 + vcg * 8,
                  Vs[(kt + 1) & 1] + (size_t)(p * 256 + w * 64) * 8);
      }
    }
    if (kt * 64 <= rw + 31) {                 // wave has at least one live sub-block
      const u16* Kc = Ks[kt & 1];
      const u16* Vc = Vs[kt & 1];
      // S^T = K Q^T: lane (n,g) reg r of block kb = S[key=kt*64+kb*16+g*4+r][q=n]
      f32x4 st[2][4];
      #pragma unroll
      for (int kb = 0; kb < 4; kb++) {
        st[0][kb] = (f32x4){0.f, 0.f, 0.f, 0.f};
        st[1][kb] = (f32x4){0.f, 0.f, 0.f, 0.f};
        #pragma unroll
        for (int c = 0; c < 2; c++) {
          int krow = kb * 16 + n;
          bf16x8 kf = *(const bf16x8*)(Kc + ((size_t)krow * 8 + (((c * 4 + g) ^ krow) & 7)) * 8);
          st[0][kb] = __builtin_amdgcn_mfma_f32_16x16x32_bf16(kf, qf[0][c], st[0][kb], 0, 0, 0);
          st[1][kb] = __builtin_amdgcn_mfma_f32_16x16x32_bf16(kf, qf[1][c], st[1][kb], 0, 0, 0);
        }
      }
      if (kt * 64 + 63 > rw) {                // diagonal straddle: mask per lane
        #pragma unroll
        for (int q2 = 0; q2 < 2; q2++)
          #pragma unroll
          for (int kb = 0; kb < 4; kb++)
            #pragma unroll
            for (int r = 0; r < 4; r++)
              if (kt * 64 + kb * 16 + g * 4 + r > rw + q2 * 16 + n) st[q2][kb][r] = -1e30f;
      }
      // exp2 + per-lane row-sum + packed b64 P write (rows padded to 72 u16)
      #pragma unroll
      for (int q2 = 0; q2 < 2; q2++) {
        int Prow = q2 * 16 + n;
        #pragma unroll
        for (int kb = 0; kb < 4; kb++) {
          float p0 = exp2f(st[q2][kb][0]), p1 = exp2f(st[q2][kb][1]);
          float p2 = exp2f(st[q2][kb][2]), p3 = exp2f(st[q2][kb][3]);
          lsum[q2] += (p0 + p1) + (p2 + p3);
          uint2 dd;
          dd.x = (uint32_t)f2bf(p0) | ((uint32_t)f2bf(p1) << 16);
          dd.y = (uint32_t)f2bf(p2) | ((uint32_t)f2bf(p3) << 16);
          *(uint2*)(Pw + (size_t)Prow * 72 + ((((kb * 2 + (g >> 1)) ^ Prow) & 7) * 8 + (g & 1) * 4)) = dd;
        }
      }
      // O += P @ V (vf read once, feeds both sub-blocks)
      #pragma unroll
      for (int c = 0; c < 2; c++) {
        bf16x8 pf0 = *(const bf16x8*)(Pw + (size_t)n * 72 + (((c * 4 + g) ^ n) & 7) * 8);
        bf16x8 pf1 = *(const bf16x8*)(Pw + (size_t)(16 + n) * 72 + (((c * 4 + g) ^ (16 + n)) & 7) * 8);
        #pragma unroll
        for (int nb = 0; nb < 8; nb++) {
          int vr = nb * 16 + n;
          bf16x8 vf = *(const bf16x8*)(Vc + ((size_t)vr * 8 + (((c * 4 + g) ^ vr) & 7)) * 8);
          o_acc[0][nb] = __builtin_amdgcn_mfma_f32_16x16x32_bf16(pf0, vf, o_acc[0][nb], 0, 0, 0);
          o_acc[1][nb] = __builtin_amdgcn_mfma_f32_16x16x32_bf16(pf1, vf, o_acc[1][nb], 0, 0, 0);
        }
      }
    }
  }
  // full row sums: reduce lane partials across the 4 g-copies of each q-row
  #pragma unroll
  for (int q2 = 0; q2 < 2; q2++) {
    lsum[q2] += __shfl_xor(lsum[q2], 16);
    lsum[q2] += __shfl_xor(lsum[q2], 32);
  }
  u16* Op = O + (size_t)inst * SEQ * 128;
  #pragma unroll
  for (int q2 = 0; q2 < 2; q2++) {
    float inv[4];
    #pragma unroll
    for (int r = 0; r < 4; r++) inv[r] = 1.0f / __shfl(lsum[q2], g * 4 + r);
    #pragma unroll
    for (int nb = 0; nb < 8; nb++)
      #pragma unroll
      for (int r = 0; r < 4; r++) {
        int qrow = rw + q2 * 16 + g * 4 + r;
        Op[(size_t)qrow * 128 + nb * 16 + n] = f2bf(o_acc[q2][nb][r] * inv[r]);
      }
  }
}

// ---------------- combine: attn1 - lam*attn2, RMSNorm(128), subln, (1-li) -----
__global__ __launch_bounds__(256) void k_combine(const u16* __restrict__ Ob,
                                                 const float* __restrict__ subw,
                                                 const float* __restrict__ lamp,
                                                 u16* __restrict__ At) {
  const int t = threadIdx.x, w = t >> 6, l = t & 63;
  const int W = blockIdx.x * 4 + w;          // (b*SEQ+s)*16 + h
  const int hh = W & 15, row = W >> 4;
  const int b = row >> 11, s = row & (SEQ - 1);
  const float lam = *lamp;
  const size_t base = ((size_t)(b * 32 + hh * 2) * SEQ + s) * 128 + 2 * l;
  uint32_t u1 = *(const uint32_t*)(Ob + base);
  uint32_t u2 = *(const uint32_t*)(Ob + base + (size_t)SEQ * 128);
  float a0 = bf2f(u1 & 0xffffu) - lam * bf2f(u2 & 0xffffu);
  float a1 = bf2f(u1 >> 16)     - lam * bf2f(u2 >> 16);
  float ss = a0 * a0 + a1 * a1;
  #pragma unroll
  for (int d = 1; d < 64; d <<= 1) ss += __shfl_xor(ss, d);
  float rms = rsqrtf(ss * (1.0f / 128.0f) + EPSF);
  float k = rms * (1.0f - LAMBDA_INIT);
  u16 r0 = f2bf(a0 * subw[2 * l] * k);
  u16 r1 = f2bf(a1 * subw[2 * l + 1] * k);
  *(uint32_t*)(At + (size_t)row * MDIM + hh * 128 + 2 * l) = (uint32_t)r0 | ((uint32_t)r1 << 16);
}

// ---------------- host ----------------
extern "C" void kernel_launch(void* const* d_in, const int* in_sizes, int n_in,
                              void* d_out, int out_size, void* d_ws, size_t ws_size,
                              hipStream_t stream) {
  const float* x    = (const float*)d_in[0];
  const float* wq   = (const float*)d_in[1];
  const float* wk   = (const float*)d_in[2];
  const float* wv   = (const float*)d_in[3];
  const float* wo   = (const float*)d_in[4];
  const float* lq1  = (const float*)d_in[5];
  const float* lk1  = (const float*)d_in[6];
  const float* lq2  = (const float*)d_in[7];
  const float* lk2  = (const float*)d_in[8];
  const float* subw = (const float*)d_in[9];
  const float* rc   = (const float*)d_in[10];
  const float* rsn  = (const float*)d_in[11];

  char* ws = (char*)d_ws;
  u16*  Xbf  = (u16*)(ws + 0);            //  16.78 MB
  u16*  Wqkv = (u16*)(ws + 16777216);     //  25.17 MB (wq|wk|wv rows)
  u16*  Wob  = (u16*)(ws + 41943040);     //   8.39 MB
  u16*  QKV  = (u16*)(ws + 50331648);     //  50.33 MB
  u16*  Qb   = (u16*)(ws + 100663296);    //  16.78 MB
  u16*  Kb   = (u16*)(ws + 117440512);    //  16.78 MB
  u16*  Vt   = (u16*)(ws + 134217728);    //  16.78 MB (tiled [bh][kt][dv][key])
  u16*  Ob   = (u16*)(ws + 150994944);    //  33.55 MB
  u16*  At   = (u16*)(ws + 184549376);    //  16.78 MB
  float* lam = (float*)(ws + 201326592);
  if (ws_size < 201326600) return;

  k_cast<<<8192, 256, 0, stream>>>((const float4*)x, Xbf, 2097152);
  k_castw<<<dim3(4096, 4), 256, 0, stream>>>((const float4*)wq, (const float4*)wk,
                                             (const float4*)wv, (const float4*)wo,
                                             Wqkv, Wqkv + 4194304, Wqkv + 8388608, Wob);

  k_gemm_bt<1><<<dim3(48, 32), 256, 0, stream>>>(Xbf, Wqkv, QKV, NROWS, QKVN, MDIM);
  k_rope<<<32768, 256, 0, stream>>>(QKV, rc, rsn, Qb, Kb);
  k_vtrans<<<dim3(32, 2, 32), 256, 0, stream>>>(QKV, Vt);
  k_lambda<<<1, 64, 0, stream>>>(lq1, lk1, lq2, lk2, lam);
  k_flash<<<1024, 256, 0, stream>>>(Qb, Kb, Vt, Ob);
  k_combine<<<16384, 256, 0, stream>>>(Ob, subw, lam, At);
  k_gemm_bt<0><<<dim3(16, 32), 256, 0, stream>>>(At, Wob, d_out, NROWS, MDIM, MDIM);
}

// Round 6
// 480.618 us; speedup vs baseline: 1.0241x; 1.0241x over previous
//
#include <hip/hip_runtime.h>
#include <stdint.h>

// Problem constants
#define SEQ   2048
#define NHEAD 16
#define DHEAD 64
#define NROWS 4096      // BSZ*SEQ
#define MDIM  2048      // model dim
#define QKVN  6144
#define EPSF  1e-5f
#define LAMBDA_INIT 0.7999593627581f
#define QSCALE 0.18033688011112042f   // dh^-0.5 * log2(e): flash softmax runs in exp2 domain

typedef unsigned short u16;
typedef __attribute__((ext_vector_type(8))) short bf16x8;   // 8 bf16 = 4 VGPRs
typedef __attribute__((ext_vector_type(4))) float f32x4;
typedef __attribute__((ext_vector_type(4))) unsigned short u16x4;

// async global->LDS, 16B/lane: data lands at LDS base + lane*16 (wave-uniform base).
#define GLD_LDS16(g, l) \
  __builtin_amdgcn_global_load_lds((const __attribute__((address_space(1))) void*)(g), \
                                   (__attribute__((address_space(3))) void*)(l), 16, 0, 0)

__device__ __forceinline__ u16 f2bf(float f) {
  union { float f; uint32_t u; } v; v.f = f;
  return (u16)((v.u + 0x7fffu + ((v.u >> 16) & 1u)) >> 16);   // RNE
}
__device__ __forceinline__ float bf2f(uint32_t s) {
  union { uint32_t u; float f; } v; v.u = s << 16; return v.f;
}

// ---------------- cast fp32 -> bf16 (vectorized) ----------------
__global__ __launch_bounds__(256) void k_cast(const float4* __restrict__ src,
                                              u16* __restrict__ dst, int n4) {
  int i = blockIdx.x * 256 + threadIdx.x;
  if (i < n4) {
    float4 f = src[i];
    u16x4 o;
    o.x = f2bf(f.x); o.y = f2bf(f.y); o.z = f2bf(f.z); o.w = f2bf(f.w);
    *(u16x4*)(dst + (size_t)i * 4) = o;
  }
}
// 4 equal-size weight casts in one launch (blockIdx.y selects tensor)
__global__ __launch_bounds__(256) void k_castw(const float4* __restrict__ s0,
                                               const float4* __restrict__ s1,
                                               const float4* __restrict__ s2,
                                               const float4* __restrict__ s3,
                                               u16* __restrict__ d0, u16* __restrict__ d1,
                                               u16* __restrict__ d2, u16* __restrict__ d3) {
  int i = blockIdx.x * 256 + threadIdx.x;
  const float4* s = blockIdx.y == 0 ? s0 : blockIdx.y == 1 ? s1 : blockIdx.y == 2 ? s2 : s3;
  u16* d = blockIdx.y == 0 ? d0 : blockIdx.y == 1 ? d1 : blockIdx.y == 2 ? d2 : d3;
  float4 f = s[i];
  u16x4 o;
  o.x = f2bf(f.x); o.y = f2bf(f.y); o.z = f2bf(f.z); o.w = f2bf(f.w);
  *(u16x4*)(d + (size_t)i * 4) = o;
}

// ---------------- BT-GEMM: C(MxN) = A(MxK) @ B(NxK)^T, bf16 in, fp32/bf16 out ----
template<int BF16OUT>
__global__ __launch_bounds__(256) void k_gemm_bt(const u16* __restrict__ A,
                                                 const u16* __restrict__ B,
                                                 void* __restrict__ Cp,
                                                 int M, int N, int K) {
  __shared__ __align__(16) u16 As[128 * 64];
  __shared__ __align__(16) u16 Bs[128 * 64];
  const int t = threadIdx.x, w = t >> 6, l = t & 63, n = l & 15, g = l >> 4;
  const int m0 = blockIdx.y * 128, n0 = blockIdx.x * 128;
  const int wm = (w >> 1) * 64, wn = (w & 1) * 64;
  f32x4 acc[4][4];
  #pragma unroll
  for (int i = 0; i < 4; i++)
    #pragma unroll
    for (int j = 0; j < 4; j++) acc[i][j] = (f32x4){0.f, 0.f, 0.f, 0.f};

  for (int kt = 0; kt < K; kt += 64) {
    #pragma unroll
    for (int p = 0; p < 4; ++p) {
      int id = p * 256 + t;
      int row = id >> 3, cc = id & 7, ccg = (cc ^ row) & 7;
      GLD_LDS16(A + (size_t)(m0 + row) * K + kt + ccg * 8, As + (size_t)(p * 256 + w * 64) * 8);
      GLD_LDS16(B + (size_t)(n0 + row) * K + kt + ccg * 8, Bs + (size_t)(p * 256 + w * 64) * 8);
    }
    __syncthreads();
    bf16x8 af[4][2], bfr[4][2];
    #pragma unroll
    for (int mi = 0; mi < 4; mi++) {
      int row = wm + mi * 16 + n;
      #pragma unroll
      for (int c = 0; c < 2; c++)
        af[mi][c] = *(const bf16x8*)(As + ((size_t)row * 8 + (((c * 4 + g) ^ row) & 7)) * 8);
    }
    #pragma unroll
    for (int ni = 0; ni < 4; ni++) {
      int row = wn + ni * 16 + n;
      #pragma unroll
      for (int c = 0; c < 2; c++)
        bfr[ni][c] = *(const bf16x8*)(Bs + ((size_t)row * 8 + (((c * 4 + g) ^ row) & 7)) * 8);
    }
    #pragma unroll
    for (int mi = 0; mi < 4; mi++)
      #pragma unroll
      for (int ni = 0; ni < 4; ni++)
        #pragma unroll
        for (int c = 0; c < 2; c++)
          acc[mi][ni] = __builtin_amdgcn_mfma_f32_16x16x32_bf16(af[mi][c], bfr[ni][c], acc[mi][ni], 0, 0, 0);
    __syncthreads();
  }
  #pragma unroll
  for (int mi = 0; mi < 4; mi++)
    #pragma unroll
    for (int ni = 0; ni < 4; ni++)
      #pragma unroll
      for (int r = 0; r < 4; r++) {
        int row = m0 + wm + mi * 16 + g * 4 + r;
        int col = n0 + wn + ni * 16 + n;
        if (BF16OUT) ((u16*)Cp)[(size_t)row * N + col] = f2bf(acc[mi][ni][r]);
        else         ((float*)Cp)[(size_t)row * N + col] = acc[mi][ni][r];
      }
}

// ---------------- RoPE + repack Q,K into per-instance layout ----------------
__global__ __launch_bounds__(256) void k_rope(const u16* __restrict__ QKV,
                                              const float* __restrict__ cosb,
                                              const float* __restrict__ sinb,
                                              u16* __restrict__ Qo, u16* __restrict__ Ko) {
  int tid = blockIdx.x * 256 + threadIdx.x;     // 2 * 4096 * 1024 = 2^23 threads
  int tensor = tid >> 22;
  int rem = tid & ((1 << 22) - 1);
  int r = rem >> 10;
  int p = rem & 1023;
  int rh = p >> 5, i = p & 31;
  int s = r & (SEQ - 1);
  int col = tensor * 2048 + rh * 64 + 2 * i;
  uint32_t u = *(const uint32_t*)(QKV + (size_t)r * QKVN + col);
  float a = bf2f(u & 0xffffu), bb = bf2f(u >> 16);
  float c = cosb[s * 32 + i], sn = sinb[s * 32 + i];
  float o0 = a * c - bb * sn;
  float o1 = a * sn + bb * c;
  if (tensor == 0) { o0 *= QSCALE; o1 *= QSCALE; }
  int inst = (r >> 11) * 32 + rh;
  u16* dst = (tensor ? Ko : Qo) + ((size_t)inst * SEQ + s) * 64 + 2 * i;
  *(uint32_t*)dst = (uint32_t)f2bf(o0) | ((uint32_t)f2bf(o1) << 16);
}

// ---------------- V transpose: QKV V-cols -> Vt TILED [bh][kt=32][128 dv][64 key]
__global__ __launch_bounds__(256) void k_vtrans(const u16* __restrict__ QKV,
                                                u16* __restrict__ Vt) {
  __shared__ __align__(16) u16 tile[64 * 80];   // pad to 160B stride
  int t = threadIdx.x;
  int st = blockIdx.x, dt = blockIdx.y, bh = blockIdx.z;
  int b = bh >> 4, h = bh & 15;
  #pragma unroll
  for (int p = 0; p < 2; p++) {
    int id = p * 256 + t, sr = id >> 3, cc = id & 7;
    const u16* gsrc = QKV + (size_t)(b * SEQ + st * 64 + sr) * QKVN + 4096 + h * 128 + dt * 64 + cc * 8;
    *(uint4*)(tile + sr * 80 + cc * 8) = *(const uint4*)gsrc;
  }
  __syncthreads();
  #pragma unroll
  for (int p = 0; p < 2; p++) {
    int id = p * 256 + t, dr = id >> 3, cc = id & 7;
    union { u16 v[8]; uint4 q; } uu;
    #pragma unroll
    for (int j = 0; j < 8; j++) uu.v[j] = tile[(cc * 8 + j) * 80 + dr];
    u16* gdst = Vt + (((size_t)bh * 32 + st) * 128 + dt * 64 + dr) * 64 + cc * 8;
    *(uint4*)gdst = uu.q;
  }
}

// ---------------- lambda scalar ----------------
__global__ __launch_bounds__(64) void k_lambda(const float* lq1, const float* lk1,
                                               const float* lq2, const float* lk2,
                                               float* out) {
  int l = threadIdx.x;
  float s1 = lq1[l] * lk1[l];
  float s2 = lq2[l] * lk2[l];
  #pragma unroll
  for (int d = 1; d < 64; d <<= 1) { s1 += __shfl_xor(s1, d); s2 += __shfl_xor(s2, d); }
  if (l == 0) *out = expf(s1) - expf(s2) + LAMBDA_INIT;
}

// ---------------- flash attention v6 (causal), dqk=64, dv=128 ----------------
// v5 structure (M=32 q-rows/wave, single barrier/k-tile, dbuf staging, S^T
// per-lane softmax) with the P buffer reverted to BANK-NEUTRAL 64-u16 rows
// (128B) + XOR chunk swizzle — v4's verified conflict-free read layout.
// v5's 72-u16 padding composed destructively with the swizzle (4-8-way
// conflicts, 19.4M cycles); padding and swizzle are alternative fixes,
// never stack them. b64 P-writes retain the structural ~1 extra cycle
// (64 lanes x 8B = 512B > 128B/cyc LDS width) — that's the floor.
__global__ __launch_bounds__(256, 2) void k_flash(const u16* __restrict__ Q,
                                                  const u16* __restrict__ K,
                                                  const u16* __restrict__ V,
                                                  u16* __restrict__ O) {
  __shared__ __align__(16) u16 Ks[2][64 * 64];
  __shared__ __align__(16) u16 Vs[2][128 * 64];
  __shared__ __align__(16) u16 Ps[4][32 * 64];
  const int t = threadIdx.x, w = t >> 6, l = t & 63, n = l & 15, g = l >> 4;
  const int gb = blockIdx.x;
  const int rem = gb & 127, xcd = rem & 7, ps = rem >> 3;
  const int inst = (gb >> 7) * 8 + xcd;
  const int qb = (15 - ps) * 128;             // longest q-tiles first
  const int b = inst >> 5, rh = inst & 31, h = rh >> 1, bh = b * 16 + h;
  const u16* Qp = Q + (size_t)inst * SEQ * 64;
  const u16* Kp = K + (size_t)inst * SEQ * 64;
  const u16* Vp = V + (size_t)bh * 32 * 128 * 64;   // tiled [kt][dv][key]
  u16* Pw = Ps[w];
  const int rw = qb + w * 32;                 // this wave's 32 q-rows

  bf16x8 qf[2][2];
  #pragma unroll
  for (int q2 = 0; q2 < 2; q2++)
    #pragma unroll
    for (int c = 0; c < 2; c++)
      qf[q2][c] = *(const bf16x8*)(Qp + (size_t)(rw + q2 * 16 + n) * 64 + c * 32 + g * 8);

  f32x4 o_acc[2][8];
  #pragma unroll
  for (int q2 = 0; q2 < 2; q2++)
    #pragma unroll
    for (int nb = 0; nb < 8; nb++) o_acc[q2][nb] = (f32x4){0.f, 0.f, 0.f, 0.f};
  float lsum[2] = {0.f, 0.f};                 // per-lane partial row sums

  const int nkt = (qb >> 6) + 2;

  // ---- stage tile 0 into buffer 0 ----
  #pragma unroll
  for (int p = 0; p < 2; p++) {
    int id = p * 256 + t, row = id >> 3, cc = id & 7, ccg = (cc ^ row) & 7;
    GLD_LDS16(Kp + (size_t)row * 64 + ccg * 8, Ks[0] + (size_t)(p * 256 + w * 64) * 8);
  }
  #pragma unroll
  for (int p = 0; p < 4; p++) {
    int id = p * 256 + t, vr = id >> 3, vc = id & 7, vcg = (vc ^ vr) & 7;
    GLD_LDS16(Vp + (size_t)vr * 64 + vcg * 8, Vs[0] + (size_t)(p * 256 + w * 64) * 8);
  }

  for (int kt = 0; kt < nkt; ++kt) {
    __syncthreads();                          // drains stage(kt); frees buf[(kt+1)&1]
    if (kt + 1 < nkt) {                       // prefetch kt+1 (in flight during compute)
      #pragma unroll
      for (int p = 0; p < 2; p++) {
        int id = p * 256 + t, row = id >> 3, cc = id & 7, ccg = (cc ^ row) & 7;
        GLD_LDS16(Kp + (size_t)((kt + 1) * 64 + row) * 64 + ccg * 8,
                  Ks[(kt + 1) & 1] + (size_t)(p * 256 + w * 64) * 8);
      }
      const u16* Vtile = Vp + (size_t)(kt + 1) * (128 * 64);
      #pragma unroll
      for (int p = 0; p < 4; p++) {
        int id = p * 256 + t, vr = id >> 3, vc = id & 7, vcg = (vc ^ vr) & 7;
        GLD_LDS16(Vtile + (size_t)vr * 64 + vcg * 8,
                  Vs[(kt + 1) & 1] + (size_t)(p * 256 + w * 64) * 8);
      }
    }
    if (kt * 64 <= rw + 31) {                 // wave has at least one live sub-block
      const u16* Kc = Ks[kt & 1];
      const u16* Vc = Vs[kt & 1];
      // S^T = K Q^T: lane (n,g) reg r of block kb = S[key=kt*64+kb*16+g*4+r][q=n]
      f32x4 st[2][4];
      #pragma unroll
      for (int kb = 0; kb < 4; kb++) {
        st[0][kb] = (f32x4){0.f, 0.f, 0.f, 0.f};
        st[1][kb] = (f32x4){0.f, 0.f, 0.f, 0.f};
        #pragma unroll
        for (int c = 0; c < 2; c++) {
          int krow = kb * 16 + n;
          bf16x8 kf = *(const bf16x8*)(Kc + ((size_t)krow * 8 + (((c * 4 + g) ^ krow) & 7)) * 8);
          st[0][kb] = __builtin_amdgcn_mfma_f32_16x16x32_bf16(kf, qf[0][c], st[0][kb], 0, 0, 0);
          st[1][kb] = __builtin_amdgcn_mfma_f32_16x16x32_bf16(kf, qf[1][c], st[1][kb], 0, 0, 0);
        }
      }
      if (kt * 64 + 63 > rw) {                // diagonal straddle: mask per lane
        #pragma unroll
        for (int q2 = 0; q2 < 2; q2++)
          #pragma unroll
          for (int kb = 0; kb < 4; kb++)
            #pragma unroll
            for (int r = 0; r < 4; r++)
              if (kt * 64 + kb * 16 + g * 4 + r > rw + q2 * 16 + n) st[q2][kb][r] = -1e30f;
      }
      // exp2 + per-lane row-sum + packed b64 P write (bank-neutral rows + swizzle)
      #pragma unroll
      for (int q2 = 0; q2 < 2; q2++) {
        int Prow = q2 * 16 + n;
        #pragma unroll
        for (int kb = 0; kb < 4; kb++) {
          float p0 = exp2f(st[q2][kb][0]), p1 = exp2f(st[q2][kb][1]);
          float p2 = exp2f(st[q2][kb][2]), p3 = exp2f(st[q2][kb][3]);
          lsum[q2] += (p0 + p1) + (p2 + p3);
          uint2 dd;
          dd.x = (uint32_t)f2bf(p0) | ((uint32_t)f2bf(p1) << 16);
          dd.y = (uint32_t)f2bf(p2) | ((uint32_t)f2bf(p3) << 16);
          *(uint2*)(Pw + (size_t)Prow * 64 + ((((kb * 2 + (g >> 1)) ^ Prow) & 7) * 8 + (g & 1) * 4)) = dd;
        }
      }
      // O += P @ V (vf read once, feeds both sub-blocks)
      #pragma unroll
      for (int c = 0; c < 2; c++) {
        bf16x8 pf0 = *(const bf16x8*)(Pw + (size_t)n * 64 + (((c * 4 + g) ^ n) & 7) * 8);
        bf16x8 pf1 = *(const bf16x8*)(Pw + (size_t)(16 + n) * 64 + (((c * 4 + g) ^ (16 + n)) & 7) * 8);
        #pragma unroll
        for (int nb = 0; nb < 8; nb++) {
          int vr = nb * 16 + n;
          bf16x8 vf = *(const bf16x8*)(Vc + ((size_t)vr * 8 + (((c * 4 + g) ^ vr) & 7)) * 8);
          o_acc[0][nb] = __builtin_amdgcn_mfma_f32_16x16x32_bf16(pf0, vf, o_acc[0][nb], 0, 0, 0);
          o_acc[1][nb] = __builtin_amdgcn_mfma_f32_16x16x32_bf16(pf1, vf, o_acc[1][nb], 0, 0, 0);
        }
      }
    }
  }
  // full row sums: reduce lane partials across the 4 g-copies of each q-row
  #pragma unroll
  for (int q2 = 0; q2 < 2; q2++) {
    lsum[q2] += __shfl_xor(lsum[q2], 16);
    lsum[q2] += __shfl_xor(lsum[q2], 32);
  }
  u16* Op = O + (size_t)inst * SEQ * 128;
  #pragma unroll
  for (int q2 = 0; q2 < 2; q2++) {
    float inv[4];
    #pragma unroll
    for (int r = 0; r < 4; r++) inv[r] = 1.0f / __shfl(lsum[q2], g * 4 + r);
    #pragma unroll
    for (int nb = 0; nb < 8; nb++)
      #pragma unroll
      for (int r = 0; r < 4; r++) {
        int qrow = rw + q2 * 16 + g * 4 + r;
        Op[(size_t)qrow * 128 + nb * 16 + n] = f2bf(o_acc[q2][nb][r] * inv[r]);
      }
  }
}

// ---------------- combine: attn1 - lam*attn2, RMSNorm(128), subln, (1-li) -----
__global__ __launch_bounds__(256) void k_combine(const u16* __restrict__ Ob,
                                                 const float* __restrict__ subw,
                                                 const float* __restrict__ lamp,
                                                 u16* __restrict__ At) {
  const int t = threadIdx.x, w = t >> 6, l = t & 63;
  const int W = blockIdx.x * 4 + w;          // (b*SEQ+s)*16 + h
  const int hh = W & 15, row = W >> 4;
  const int b = row >> 11, s = row & (SEQ - 1);
  const float lam = *lamp;
  const size_t base = ((size_t)(b * 32 + hh * 2) * SEQ + s) * 128 + 2 * l;
  uint32_t u1 = *(const uint32_t*)(Ob + base);
  uint32_t u2 = *(const uint32_t*)(Ob + base + (size_t)SEQ * 128);
  float a0 = bf2f(u1 & 0xffffu) - lam * bf2f(u2 & 0xffffu);
  float a1 = bf2f(u1 >> 16)     - lam * bf2f(u2 >> 16);
  float ss = a0 * a0 + a1 * a1;
  #pragma unroll
  for (int d = 1; d < 64; d <<= 1) ss += __shfl_xor(ss, d);
  float rms = rsqrtf(ss * (1.0f / 128.0f) + EPSF);
  float k = rms * (1.0f - LAMBDA_INIT);
  u16 r0 = f2bf(a0 * subw[2 * l] * k);
  u16 r1 = f2bf(a1 * subw[2 * l + 1] * k);
  *(uint32_t*)(At + (size_t)row * MDIM + hh * 128 + 2 * l) = (uint32_t)r0 | ((uint32_t)r1 << 16);
}

// ---------------- host ----------------
extern "C" void kernel_launch(void* const* d_in, const int* in_sizes, int n_in,
                              void* d_out, int out_size, void* d_ws, size_t ws_size,
                              hipStream_t stream) {
  const float* x    = (const float*)d_in[0];
  const float* wq   = (const float*)d_in[1];
  const float* wk   = (const float*)d_in[2];
  const float* wv   = (const float*)d_in[3];
  const float* wo   = (const float*)d_in[4];
  const float* lq1  = (const float*)d_in[5];
  const float* lk1  = (const float*)d_in[6];
  const float* lq2  = (const float*)d_in[7];
  const float* lk2  = (const float*)d_in[8];
  const float* subw = (const float*)d_in[9];
  const float* rc   = (const float*)d_in[10];
  const float* rsn  = (const float*)d_in[11];

  char* ws = (char*)d_ws;
  u16*  Xbf  = (u16*)(ws + 0);            //  16.78 MB
  u16*  Wqkv = (u16*)(ws + 16777216);     //  25.17 MB (wq|wk|wv rows)
  u16*  Wob  = (u16*)(ws + 41943040);     //   8.39 MB
  u16*  QKV  = (u16*)(ws + 50331648);     //  50.33 MB
  u16*  Qb   = (u16*)(ws + 100663296);    //  16.78 MB
  u16*  Kb   = (u16*)(ws + 117440512);    //  16.78 MB
  u16*  Vt   = (u16*)(ws + 134217728);    //  16.78 MB (tiled [bh][kt][dv][key])
  u16*  Ob   = (u16*)(ws + 150994944);    //  33.55 MB
  u16*  At   = (u16*)(ws + 184549376);    //  16.78 MB
  float* lam = (float*)(ws + 201326592);
  if (ws_size < 201326600) return;

  k_cast<<<8192, 256, 0, stream>>>((const float4*)x, Xbf, 2097152);
  k_castw<<<dim3(4096, 4), 256, 0, stream>>>((const float4*)wq, (const float4*)wk,
                                             (const float4*)wv, (const float4*)wo,
                                             Wqkv, Wqkv + 4194304, Wqkv + 8388608, Wob);

  k_gemm_bt<1><<<dim3(48, 32), 256, 0, stream>>>(Xbf, Wqkv, QKV, NROWS, QKVN, MDIM);
  k_rope<<<32768, 256, 0, stream>>>(QKV, rc, rsn, Qb, Kb);
  k_vtrans<<<dim3(32, 2, 32), 256, 0, stream>>>(QKV, Vt);
  k_lambda<<<1, 64, 0, stream>>>(lq1, lk1, lq2, lk2, lam);
  k_flash<<<1024, 256, 0, stream>>>(Qb, Kb, Vt, Ob);
  k_combine<<<16384, 256, 0, stream>>>(Ob, subw, lam, At);
  k_gemm_bt<0><<<dim3(16, 32), 256, 0, stream>>>(At, Wob, d_out, NROWS, MDIM, MDIM);
}

// Round 7
// 468.925 us; speedup vs baseline: 1.0496x; 1.0249x over previous
//
#include <hip/hip_runtime.h>
#include <stdint.h>

// Problem constants
#define SEQ   2048
#define NHEAD 16
#define DHEAD 64
#define NROWS 4096      // BSZ*SEQ
#define MDIM  2048      // model dim
#define QKVN  6144
#define EPSF  1e-5f
#define LAMBDA_INIT 0.7999593627581f
#define QSCALE 0.18033688011112042f   // dh^-0.5 * log2(e): flash softmax runs in exp2 domain

typedef unsigned short u16;
typedef __attribute__((ext_vector_type(8))) short bf16x8;   // 8 bf16 = 4 VGPRs
typedef __attribute__((ext_vector_type(4))) float f32x4;
typedef __attribute__((ext_vector_type(4))) unsigned short u16x4;

// async global->LDS, 16B/lane: data lands at LDS base + lane*16 (wave-uniform base).
#define GLD_LDS16(g, l) \
  __builtin_amdgcn_global_load_lds((const __attribute__((address_space(1))) void*)(g), \
                                   (__attribute__((address_space(3))) void*)(l), 16, 0, 0)

__device__ __forceinline__ u16 f2bf(float f) {
  union { float f; uint32_t u; } v; v.f = f;
  return (u16)((v.u + 0x7fffu + ((v.u >> 16) & 1u)) >> 16);   // RNE
}
__device__ __forceinline__ float bf2f(uint32_t s) {
  union { uint32_t u; float f; } v; v.u = s << 16; return v.f;
}

// ---------------- cast fp32 -> bf16 (vectorized) ----------------
__global__ __launch_bounds__(256) void k_cast(const float4* __restrict__ src,
                                              u16* __restrict__ dst, int n4) {
  int i = blockIdx.x * 256 + threadIdx.x;
  if (i < n4) {
    float4 f = src[i];
    u16x4 o;
    o.x = f2bf(f.x); o.y = f2bf(f.y); o.z = f2bf(f.z); o.w = f2bf(f.w);
    *(u16x4*)(dst + (size_t)i * 4) = o;
  }
}
// 4 equal-size weight casts in one launch (blockIdx.y selects tensor)
__global__ __launch_bounds__(256) void k_castw(const float4* __restrict__ s0,
                                               const float4* __restrict__ s1,
                                               const float4* __restrict__ s2,
                                               const float4* __restrict__ s3,
                                               u16* __restrict__ d0, u16* __restrict__ d1,
                                               u16* __restrict__ d2, u16* __restrict__ d3) {
  int i = blockIdx.x * 256 + threadIdx.x;
  const float4* s = blockIdx.y == 0 ? s0 : blockIdx.y == 1 ? s1 : blockIdx.y == 2 ? s2 : s3;
  u16* d = blockIdx.y == 0 ? d0 : blockIdx.y == 1 ? d1 : blockIdx.y == 2 ? d2 : d3;
  float4 f = s[i];
  u16x4 o;
  o.x = f2bf(f.x); o.y = f2bf(f.y); o.z = f2bf(f.z); o.w = f2bf(f.w);
  *(u16x4*)(d + (size_t)i * 4) = o;
}

// ---------------- BT-GEMM: C(MxN) = A(MxK) @ B(NxK)^T, bf16 in, fp32/bf16 out ----
template<int BF16OUT>
__global__ __launch_bounds__(256) void k_gemm_bt(const u16* __restrict__ A,
                                                 const u16* __restrict__ B,
                                                 void* __restrict__ Cp,
                                                 int M, int N, int K) {
  __shared__ __align__(16) u16 As[128 * 64];
  __shared__ __align__(16) u16 Bs[128 * 64];
  const int t = threadIdx.x, w = t >> 6, l = t & 63, n = l & 15, g = l >> 4;
  const int m0 = blockIdx.y * 128, n0 = blockIdx.x * 128;
  const int wm = (w >> 1) * 64, wn = (w & 1) * 64;
  f32x4 acc[4][4];
  #pragma unroll
  for (int i = 0; i < 4; i++)
    #pragma unroll
    for (int j = 0; j < 4; j++) acc[i][j] = (f32x4){0.f, 0.f, 0.f, 0.f};

  for (int kt = 0; kt < K; kt += 64) {
    #pragma unroll
    for (int p = 0; p < 4; ++p) {
      int id = p * 256 + t;
      int row = id >> 3, cc = id & 7, ccg = (cc ^ row) & 7;
      GLD_LDS16(A + (size_t)(m0 + row) * K + kt + ccg * 8, As + (size_t)(p * 256 + w * 64) * 8);
      GLD_LDS16(B + (size_t)(n0 + row) * K + kt + ccg * 8, Bs + (size_t)(p * 256 + w * 64) * 8);
    }
    __syncthreads();
    bf16x8 af[4][2], bfr[4][2];
    #pragma unroll
    for (int mi = 0; mi < 4; mi++) {
      int row = wm + mi * 16 + n;
      #pragma unroll
      for (int c = 0; c < 2; c++)
        af[mi][c] = *(const bf16x8*)(As + ((size_t)row * 8 + (((c * 4 + g) ^ row) & 7)) * 8);
    }
    #pragma unroll
    for (int ni = 0; ni < 4; ni++) {
      int row = wn + ni * 16 + n;
      #pragma unroll
      for (int c = 0; c < 2; c++)
        bfr[ni][c] = *(const bf16x8*)(Bs + ((size_t)row * 8 + (((c * 4 + g) ^ row) & 7)) * 8);
    }
    #pragma unroll
    for (int mi = 0; mi < 4; mi++)
      #pragma unroll
      for (int ni = 0; ni < 4; ni++)
        #pragma unroll
        for (int c = 0; c < 2; c++)
          acc[mi][ni] = __builtin_amdgcn_mfma_f32_16x16x32_bf16(af[mi][c], bfr[ni][c], acc[mi][ni], 0, 0, 0);
    __syncthreads();
  }
  #pragma unroll
  for (int mi = 0; mi < 4; mi++)
    #pragma unroll
    for (int ni = 0; ni < 4; ni++)
      #pragma unroll
      for (int r = 0; r < 4; r++) {
        int row = m0 + wm + mi * 16 + g * 4 + r;
        int col = n0 + wn + ni * 16 + n;
        if (BF16OUT) ((u16*)Cp)[(size_t)row * N + col] = f2bf(acc[mi][ni][r]);
        else         ((float*)Cp)[(size_t)row * N + col] = acc[mi][ni][r];
      }
}

// ---------------- RoPE + repack Q,K into per-instance layout ----------------
__global__ __launch_bounds__(256) void k_rope(const u16* __restrict__ QKV,
                                              const float* __restrict__ cosb,
                                              const float* __restrict__ sinb,
                                              u16* __restrict__ Qo, u16* __restrict__ Ko) {
  int tid = blockIdx.x * 256 + threadIdx.x;     // 2 * 4096 * 1024 = 2^23 threads
  int tensor = tid >> 22;
  int rem = tid & ((1 << 22) - 1);
  int r = rem >> 10;
  int p = rem & 1023;
  int rh = p >> 5, i = p & 31;
  int s = r & (SEQ - 1);
  int col = tensor * 2048 + rh * 64 + 2 * i;
  uint32_t u = *(const uint32_t*)(QKV + (size_t)r * QKVN + col);
  float a = bf2f(u & 0xffffu), bb = bf2f(u >> 16);
  float c = cosb[s * 32 + i], sn = sinb[s * 32 + i];
  float o0 = a * c - bb * sn;
  float o1 = a * sn + bb * c;
  if (tensor == 0) { o0 *= QSCALE; o1 *= QSCALE; }
  int inst = (r >> 11) * 32 + rh;
  u16* dst = (tensor ? Ko : Qo) + ((size_t)inst * SEQ + s) * 64 + 2 * i;
  *(uint32_t*)dst = (uint32_t)f2bf(o0) | ((uint32_t)f2bf(o1) << 16);
}

// ---------------- V transpose: QKV V-cols -> Vt TILED [bh][kt32=64][128 dv][32 key]
// (each (bh,kt32) tile is 8KB contiguous -> flash staging lane-contiguous)
__global__ __launch_bounds__(256) void k_vtrans(const u16* __restrict__ QKV,
                                                u16* __restrict__ Vt) {
  __shared__ __align__(16) u16 tile[64 * 80];   // pad to 160B stride
  int t = threadIdx.x;
  int st = blockIdx.x, dt = blockIdx.y, bh = blockIdx.z;
  int b = bh >> 4, h = bh & 15;
  #pragma unroll
  for (int p = 0; p < 2; p++) {
    int id = p * 256 + t, sr = id >> 3, cc = id & 7;
    const u16* gsrc = QKV + (size_t)(b * SEQ + st * 64 + sr) * QKVN + 4096 + h * 128 + dt * 64 + cc * 8;
    *(uint4*)(tile + sr * 80 + cc * 8) = *(const uint4*)gsrc;
  }
  __syncthreads();
  #pragma unroll
  for (int p = 0; p < 2; p++) {
    int id = p * 256 + t, dr = id >> 3, cc = id & 7;   // dr = dv-in-half, key chunk cc*8
    union { u16 v[8]; uint4 q; } uu;
    #pragma unroll
    for (int j = 0; j < 8; j++) uu.v[j] = tile[(cc * 8 + j) * 80 + dr];
    // global key = st*64 + cc*8 + j -> kt32 = st*2 + (cc>>2), key-in-32 = (cc&3)*8
    u16* gdst = Vt + ((((size_t)bh * 64 + st * 2 + (cc >> 2)) * 128 + dt * 64 + dr) * 32) + (cc & 3) * 8;
    *(uint4*)gdst = uu.q;
  }
}

// ---------------- lambda scalar ----------------
__global__ __launch_bounds__(64) void k_lambda(const float* lq1, const float* lk1,
                                               const float* lq2, const float* lk2,
                                               float* out) {
  int l = threadIdx.x;
  float s1 = lq1[l] * lk1[l];
  float s2 = lq2[l] * lk2[l];
  #pragma unroll
  for (int d = 1; d < 64; d <<= 1) { s1 += __shfl_xor(s1, d); s2 += __shfl_xor(s2, d); }
  if (l == 0) *out = expf(s1) - expf(s2) + LAMBDA_INIT;
}

// ---------------- flash attention v7 (causal, split-K balanced), dqk=64, dv=128
// BK=32 k-tiles -> LDS 32KB -> 4 blocks/CU = 16 waves/CU (4/SIMD) at M=32/wave.
// Balanced split-K: job j = (tile 15-j, ktiles [0,32-2j)) + (tile j, ktiles
// [2j+2,4j+4)) — EXACTLY 34 ktile32s per job; 1024 equal jobs = 1024 resident
// slots: zero tail. Softmax has no max-subtraction -> partials combine by pure
// ADDITION: O=(Oa+Ob)/(la+lb) in k_combine. Partial O bf16 + lsum fp32 written
// to dead ws regions. Swizzles: K chunk^(row&7); V key-chunk^(dv&3); P 8B-slot
// ^(q&6) (bit0-preserving so the pf b128 read keeps key order).
__global__ __launch_bounds__(256, 4) void k_flash(const u16* __restrict__ Q,
                                                  const u16* __restrict__ K,
                                                  const u16* __restrict__ V,
                                                  u16* __restrict__ PA, u16* __restrict__ PB,
                                                  float* __restrict__ LA, float* __restrict__ LB) {
  __shared__ __align__(16) u16 Ks[2][32 * 64];
  __shared__ __align__(16) u16 Vs[2][128 * 32];
  __shared__ __align__(16) u16 Ps[4][32 * 32];
  const int t = threadIdx.x, w = t >> 6, l = t & 63, n = l & 15, g = l >> 4;
  const int gb = blockIdx.x;
  const int xcd = gb & 7, qq = gb >> 3, j = qq & 15, ihi = qq >> 4;
  const int inst = ihi * 8 + xcd;                    // 16 jobs of an inst share an XCD
  const int b = inst >> 5, rh = inst & 31, h = rh >> 1, bh = b * 16 + h;
  const u16* Qp = Q + (size_t)inst * SEQ * 64;
  const u16* Kp = K + (size_t)inst * SEQ * 64;
  const u16* Vp = V + (size_t)bh * 262144;           // [kt32=64][128][32]
  u16* Pw = Ps[w];

  #pragma unroll
  for (int ch = 0; ch < 2; ch++) {
    const int tile = ch ? j : (15 - j);
    const int k0 = ch ? (2 * j + 2) : 0;
    const int k1 = ch ? (4 * j + 4) : (32 - 2 * j);
    const int rw = tile * 128 + w * 32;              // this wave's 32 q-rows
    u16* Od = ch ? PB : PA;
    float* Ld = ch ? LB : LA;

    bf16x8 qf[2][2];
    #pragma unroll
    for (int q2 = 0; q2 < 2; q2++)
      #pragma unroll
      for (int c = 0; c < 2; c++)
        qf[q2][c] = *(const bf16x8*)(Qp + (size_t)(rw + q2 * 16 + n) * 64 + c * 32 + g * 8);

    f32x4 o_acc[2][8];
    #pragma unroll
    for (int q2 = 0; q2 < 2; q2++)
      #pragma unroll
      for (int nb = 0; nb < 8; nb++) o_acc[q2][nb] = (f32x4){0.f, 0.f, 0.f, 0.f};
    float lsum[2] = {0.f, 0.f};

    __syncthreads();                                 // LDS safe to restage (chunk boundary)
    {   // stage k0 -> buffer 0
      int row = t >> 3, cc = t & 7, ccg = cc ^ (row & 7);
      GLD_LDS16(Kp + (size_t)(k0 * 32 + row) * 64 + ccg * 8, Ks[0] + (size_t)w * 512);
      #pragma unroll
      for (int p = 0; p < 2; p++) {
        int id = p * 256 + t, vr = id >> 2, vc = id & 3, vcg = vc ^ (vr & 3);
        GLD_LDS16(Vp + (size_t)k0 * 4096 + vr * 32 + vcg * 8, Vs[0] + (size_t)(p * 256 + w * 64) * 8);
      }
    }

    for (int kt = k0; kt < k1; ++kt) {
      const int par = (kt - k0) & 1;
      __syncthreads();                               // drains stage(kt)
      if (kt + 1 < k1) {                             // prefetch kt+1 into other buffer
        int row = t >> 3, cc = t & 7, ccg = cc ^ (row & 7);
        GLD_LDS16(Kp + (size_t)((kt + 1) * 32 + row) * 64 + ccg * 8,
                  Ks[par ^ 1] + (size_t)w * 512);
        const u16* Vtile = Vp + (size_t)(kt + 1) * 4096;
        #pragma unroll
        for (int p = 0; p < 2; p++) {
          int id = p * 256 + t, vr = id >> 2, vc = id & 3, vcg = vc ^ (vr & 3);
          GLD_LDS16(Vtile + (size_t)vr * 32 + vcg * 8, Vs[par ^ 1] + (size_t)(p * 256 + w * 64) * 8);
        }
      }
      if (kt * 32 <= rw + 31) {                      // wave not fully masked
        const u16* Kc = Ks[par];
        const u16* Vc = Vs[par];
        // S^T = K Q^T: lane (n,g) reg r of kb2 = S[key=kt*32+kb2*16+g*4+r][q=n]
        f32x4 st[2][2];
        st[0][0] = st[0][1] = st[1][0] = st[1][1] = (f32x4){0.f, 0.f, 0.f, 0.f};
        #pragma unroll
        for (int kb2 = 0; kb2 < 2; kb2++) {
          int krow = kb2 * 16 + n;
          #pragma unroll
          for (int c = 0; c < 2; c++) {
            bf16x8 kf = *(const bf16x8*)(Kc + (size_t)krow * 64 + (((c * 4 + g) ^ (n & 7)) * 8));
            st[0][kb2] = __builtin_amdgcn_mfma_f32_16x16x32_bf16(kf, qf[0][c], st[0][kb2], 0, 0, 0);
            st[1][kb2] = __builtin_amdgcn_mfma_f32_16x16x32_bf16(kf, qf[1][c], st[1][kb2], 0, 0, 0);
          }
        }
        if (kt * 32 + 31 > rw) {                     // diagonal straddle: mask
          #pragma unroll
          for (int q2 = 0; q2 < 2; q2++)
            #pragma unroll
            for (int kb2 = 0; kb2 < 2; kb2++)
              #pragma unroll
              for (int r = 0; r < 4; r++)
                if (kt * 32 + kb2 * 16 + g * 4 + r > rw + q2 * 16 + n) st[q2][kb2][r] = -1e30f;
        }
        // exp2 + per-lane row-sum + packed b64 P write (slot ^ (q&6))
        #pragma unroll
        for (int q2 = 0; q2 < 2; q2++) {
          int Prow = q2 * 16 + n;
          #pragma unroll
          for (int kb2 = 0; kb2 < 2; kb2++) {
            float p0 = exp2f(st[q2][kb2][0]), p1 = exp2f(st[q2][kb2][1]);
            float p2 = exp2f(st[q2][kb2][2]), p3 = exp2f(st[q2][kb2][3]);
            lsum[q2] += (p0 + p1) + (p2 + p3);
            uint2 dd;
            dd.x = (uint32_t)f2bf(p0) | ((uint32_t)f2bf(p1) << 16);
            dd.y = (uint32_t)f2bf(p2) | ((uint32_t)f2bf(p3) << 16);
            *(uint2*)(Pw + (size_t)Prow * 32 + (((kb2 * 4 + g) ^ (n & 6)) * 4)) = dd;
          }
        }
        // O += P @ V : one MFMA per (q2,nb); vf shared across q2
        bf16x8 pf0 = *(const bf16x8*)(Pw + (size_t)n * 32 + (((2 * g) ^ (n & 6)) * 4));
        bf16x8 pf1 = *(const bf16x8*)(Pw + (size_t)(16 + n) * 32 + (((2 * g) ^ (n & 6)) * 4));
        #pragma unroll
        for (int nb = 0; nb < 8; nb++) {
          int dv = nb * 16 + n;
          bf16x8 vf = *(const bf16x8*)(Vc + (size_t)dv * 32 + ((g ^ (n & 3)) * 8));
          o_acc[0][nb] = __builtin_amdgcn_mfma_f32_16x16x32_bf16(pf0, vf, o_acc[0][nb], 0, 0, 0);
          o_acc[1][nb] = __builtin_amdgcn_mfma_f32_16x16x32_bf16(pf1, vf, o_acc[1][nb], 0, 0, 0);
        }
      }
    }
    // epilogue: reduce lsum over the 4 g-copies; write UNNORMALIZED partials
    #pragma unroll
    for (int q2 = 0; q2 < 2; q2++) {
      lsum[q2] += __shfl_xor(lsum[q2], 16);
      lsum[q2] += __shfl_xor(lsum[q2], 32);
    }
    u16* Op = Od + (size_t)inst * SEQ * 128;
    #pragma unroll
    for (int q2 = 0; q2 < 2; q2++)
      #pragma unroll
      for (int nb = 0; nb < 8; nb++)
        #pragma unroll
        for (int r = 0; r < 4; r++) {
          int qrow = rw + q2 * 16 + g * 4 + r;
          Op[(size_t)qrow * 128 + nb * 16 + n] = f2bf(o_acc[q2][nb][r]);
        }
    if (l < 16) {                                    // g==0 lanes hold row sums
      Ld[(size_t)inst * SEQ + rw + n]      = lsum[0];
      Ld[(size_t)inst * SEQ + rw + 16 + n] = lsum[1];
    }
  }
}

// ---------------- combine: merge split-K partials, attn1 - lam*attn2,
// RMSNorm(128), subln, (1-lambda_init) ----------------
__global__ __launch_bounds__(256) void k_combine(const u16* __restrict__ PA,
                                                 const u16* __restrict__ PB,
                                                 const float* __restrict__ LA,
                                                 const float* __restrict__ LB,
                                                 const float* __restrict__ subw,
                                                 const float* __restrict__ lamp,
                                                 u16* __restrict__ At) {
  const int t = threadIdx.x, w = t >> 6, l = t & 63;
  const int W = blockIdx.x * 4 + w;          // (b*SEQ+s)*16 + h
  const int hh = W & 15, row = W >> 4;
  const int b = row >> 11, s = row & (SEQ - 1);
  const float lam = *lamp;
  const int e1 = b * 32 + hh * 2;
  const size_t base1 = ((size_t)e1 * SEQ + s) * 128 + 2 * l;
  const size_t base2 = base1 + (size_t)SEQ * 128;
  uint32_t u1a = *(const uint32_t*)(PA + base1);
  uint32_t u1b = *(const uint32_t*)(PB + base1);
  uint32_t u2a = *(const uint32_t*)(PA + base2);
  uint32_t u2b = *(const uint32_t*)(PB + base2);
  float inv1 = 1.0f / (LA[(size_t)e1 * SEQ + s] + LB[(size_t)e1 * SEQ + s]);
  float inv2 = 1.0f / (LA[(size_t)(e1 + 1) * SEQ + s] + LB[(size_t)(e1 + 1) * SEQ + s]);
  float o10 = (bf2f(u1a & 0xffffu) + bf2f(u1b & 0xffffu)) * inv1;
  float o11 = (bf2f(u1a >> 16) + bf2f(u1b >> 16)) * inv1;
  float o20 = (bf2f(u2a & 0xffffu) + bf2f(u2b & 0xffffu)) * inv2;
  float o21 = (bf2f(u2a >> 16) + bf2f(u2b >> 16)) * inv2;
  float a0 = o10 - lam * o20;
  float a1 = o11 - lam * o21;
  float ss = a0 * a0 + a1 * a1;
  #pragma unroll
  for (int d = 1; d < 64; d <<= 1) ss += __shfl_xor(ss, d);
  float rms = rsqrtf(ss * (1.0f / 128.0f) + EPSF);
  float k = rms * (1.0f - LAMBDA_INIT);
  u16 r0 = f2bf(a0 * subw[2 * l] * k);
  u16 r1 = f2bf(a1 * subw[2 * l + 1] * k);
  *(uint32_t*)(At + (size_t)row * MDIM + hh * 128 + 2 * l) = (uint32_t)r0 | ((uint32_t)r1 << 16);
}

// ---------------- host ----------------
extern "C" void kernel_launch(void* const* d_in, const int* in_sizes, int n_in,
                              void* d_out, int out_size, void* d_ws, size_t ws_size,
                              hipStream_t stream) {
  const float* x    = (const float*)d_in[0];
  const float* wq   = (const float*)d_in[1];
  const float* wk   = (const float*)d_in[2];
  const float* wv   = (const float*)d_in[3];
  const float* wo   = (const float*)d_in[4];
  const float* lq1  = (const float*)d_in[5];
  const float* lk1  = (const float*)d_in[6];
  const float* lq2  = (const float*)d_in[7];
  const float* lk2  = (const float*)d_in[8];
  const float* subw = (const float*)d_in[9];
  const float* rc   = (const float*)d_in[10];
  const float* rsn  = (const float*)d_in[11];

  char* ws = (char*)d_ws;
  u16*  Xbf  = (u16*)(ws + 0);            //  16.78 MB (dead after GEMM1 -> hosts LA/LB)
  u16*  Wqkv = (u16*)(ws + 16777216);     //  25.17 MB (wq|wk|wv rows)
  u16*  Wob  = (u16*)(ws + 41943040);     //   8.39 MB
  u16*  QKV  = (u16*)(ws + 50331648);     //  50.33 MB (dead after rope/vtrans -> hosts PB)
  u16*  Qb   = (u16*)(ws + 100663296);    //  16.78 MB
  u16*  Kb   = (u16*)(ws + 117440512);    //  16.78 MB
  u16*  Vt   = (u16*)(ws + 134217728);    //  16.78 MB (tiled [bh][kt32][dv][key])
  u16*  ObA  = (u16*)(ws + 150994944);    //  33.55 MB (split-K partial A)
  u16*  At   = (u16*)(ws + 184549376);    //  16.78 MB
  float* lam = (float*)(ws + 201326592);
  u16*  ObB  = QKV;                       //  33.55 MB partial B aliases dead QKV
  float* LA  = (float*)(ws + 0);          //  512 KB  aliases dead Xbf
  float* LB  = (float*)(ws + 524288);     //  512 KB
  if (ws_size < 201326600) return;

  k_cast<<<8192, 256, 0, stream>>>((const float4*)x, Xbf, 2097152);
  k_castw<<<dim3(4096, 4), 256, 0, stream>>>((const float4*)wq, (const float4*)wk,
                                             (const float4*)wv, (const float4*)wo,
                                             Wqkv, Wqkv + 4194304, Wqkv + 8388608, Wob);

  k_gemm_bt<1><<<dim3(48, 32), 256, 0, stream>>>(Xbf, Wqkv, QKV, NROWS, QKVN, MDIM);
  k_rope<<<32768, 256, 0, stream>>>(QKV, rc, rsn, Qb, Kb);
  k_vtrans<<<dim3(32, 2, 32), 256, 0, stream>>>(QKV, Vt);
  k_lambda<<<1, 64, 0, stream>>>(lq1, lk1, lq2, lk2, lam);
  k_flash<<<1024, 256, 0, stream>>>(Qb, Kb, Vt, ObA, ObB, LA, LB);
  k_combine<<<16384, 256, 0, stream>>>(ObA, ObB, LA, LB, subw, lam, At);
  k_gemm_bt<0><<<dim3(16, 32), 256, 0, stream>>>(At, Wob, d_out, NROWS, MDIM, MDIM);
}

// Round 8
// 463.214 us; speedup vs baseline: 1.0626x; 1.0123x over previous
//
#include <hip/hip_runtime.h>
#include <hip/hip_bf16.h>
#include <stdint.h>

// Problem constants
#define SEQ   2048
#define NHEAD 16
#define DHEAD 64
#define NROWS 4096      // BSZ*SEQ
#define MDIM  2048      // model dim
#define QKVN  6144
#define EPSF  1e-5f
#define LAMBDA_INIT 0.7999593627581f
#define QSCALE 0.18033688011112042f   // dh^-0.5 * log2(e): flash softmax runs in exp2 domain

typedef unsigned short u16;
typedef __attribute__((ext_vector_type(8))) short bf16x8;   // 8 bf16 = 4 VGPRs
typedef __attribute__((ext_vector_type(4))) float f32x4;
typedef __attribute__((ext_vector_type(4))) unsigned short u16x4;

// async global->LDS, 16B/lane: data lands at LDS base + lane*16 (wave-uniform base).
#define GLD_LDS16(g, l) \
  __builtin_amdgcn_global_load_lds((const __attribute__((address_space(1))) void*)(g), \
                                   (__attribute__((address_space(3))) void*)(l), 16, 0, 0)

__device__ __forceinline__ u16 f2bf(float f) {
  union { float f; uint32_t u; } v; v.f = f;
  return (u16)((v.u + 0x7fffu + ((v.u >> 16) & 1u)) >> 16);   // RNE
}
__device__ __forceinline__ float bf2f(uint32_t s) {
  union { uint32_t u; float f; } v; v.u = s << 16; return v.f;
}
// packed fp32x2 -> bf16x2 (gfx950 v_cvt_pk_bf16_f32 via HIP API), RNE
__device__ __forceinline__ uint32_t pk2(float a, float b) {
  __hip_bfloat162 h = __float22bfloat162_rn(make_float2(a, b));
  union { __hip_bfloat162 h; uint32_t u; } v; v.h = h; return v.u;
}

// ---------------- unified cast: x, 4 weights, cos/sin float2 table ----------
__global__ __launch_bounds__(256) void k_castall(const float4* __restrict__ x,
                                                 const float4* __restrict__ wq,
                                                 const float4* __restrict__ wk,
                                                 const float4* __restrict__ wv,
                                                 const float4* __restrict__ wo,
                                                 const float4* __restrict__ rc,
                                                 const float4* __restrict__ rsn,
                                                 u16* __restrict__ Xbf,
                                                 u16* __restrict__ Wqkv,
                                                 u16* __restrict__ Wob,
                                                 float4* __restrict__ CS) {
  int bid = blockIdx.x, t = threadIdx.x;
  if (bid < 8192) {                       // x: 2.097M float4
    int i = bid * 256 + t;
    float4 f = x[i];
    u16x4 o; o.x = f2bf(f.x); o.y = f2bf(f.y); o.z = f2bf(f.z); o.w = f2bf(f.w);
    *(u16x4*)(Xbf + (size_t)i * 4) = o;
  } else if (bid < 24576) {               // 4 weights x 1.048M float4
    int widx = (bid - 8192) >> 12;
    int i = ((bid - 8192) & 4095) * 256 + t;
    const float4* s = widx == 0 ? wq : widx == 1 ? wk : widx == 2 ? wv : wo;
    u16* d = widx < 3 ? (Wqkv + (size_t)widx * 4194304) : Wob;
    float4 f = s[i];
    u16x4 o; o.x = f2bf(f.x); o.y = f2bf(f.y); o.z = f2bf(f.z); o.w = f2bf(f.w);
    *(u16x4*)(d + (size_t)i * 4) = o;
  } else {                                // CS[s*32+i] = (cos, sin) float2; 16384 f4
    int j = (bid - 24576) * 256 + t;
    float4 c = rc[j], s = rsn[j];
    CS[(size_t)j * 2]     = make_float4(c.x, s.x, c.y, s.y);
    CS[(size_t)j * 2 + 1] = make_float4(c.z, s.z, c.w, s.w);
  }
}

// ---------------- GEMM1 + fused RoPE epilogue: QKV = Xbf @ Wqkv^T ------------
// Q/K cols: rope rotation via __shfl_xor(val,1) partner exchange + CS float2
// table, written straight to flash layouts Qb/Kb (Q pre-scaled by QSCALE).
// V cols: plain bf16 to compact Vbuf[row][2048].
__global__ __launch_bounds__(256) void k_gemm_qkv(const u16* __restrict__ A,
                                                  const u16* __restrict__ B,
                                                  const float2* __restrict__ CS2,
                                                  u16* __restrict__ Qb,
                                                  u16* __restrict__ Kb,
                                                  u16* __restrict__ Vbuf) {
  __shared__ __align__(16) u16 As[128 * 64];
  __shared__ __align__(16) u16 Bs[128 * 64];
  const int t = threadIdx.x, w = t >> 6, l = t & 63, n = l & 15, g = l >> 4;
  const int m0 = blockIdx.y * 128, n0 = blockIdx.x * 128;
  const int wm = (w >> 1) * 64, wn = (w & 1) * 64;
  f32x4 acc[4][4];
  #pragma unroll
  for (int i = 0; i < 4; i++)
    #pragma unroll
    for (int j = 0; j < 4; j++) acc[i][j] = (f32x4){0.f, 0.f, 0.f, 0.f};

  for (int kt = 0; kt < MDIM; kt += 64) {
    #pragma unroll
    for (int p = 0; p < 4; ++p) {
      int id = p * 256 + t;
      int row = id >> 3, cc = id & 7, ccg = (cc ^ row) & 7;
      GLD_LDS16(A + (size_t)(m0 + row) * MDIM + kt + ccg * 8, As + (size_t)(p * 256 + w * 64) * 8);
      GLD_LDS16(B + (size_t)(n0 + row) * MDIM + kt + ccg * 8, Bs + (size_t)(p * 256 + w * 64) * 8);
    }
    __syncthreads();
    bf16x8 af[4][2], bfr[4][2];
    #pragma unroll
    for (int mi = 0; mi < 4; mi++) {
      int row = wm + mi * 16 + n;
      #pragma unroll
      for (int c = 0; c < 2; c++)
        af[mi][c] = *(const bf16x8*)(As + ((size_t)row * 8 + (((c * 4 + g) ^ row) & 7)) * 8);
    }
    #pragma unroll
    for (int ni = 0; ni < 4; ni++) {
      int row = wn + ni * 16 + n;
      #pragma unroll
      for (int c = 0; c < 2; c++)
        bfr[ni][c] = *(const bf16x8*)(Bs + ((size_t)row * 8 + (((c * 4 + g) ^ row) & 7)) * 8);
    }
    #pragma unroll
    for (int mi = 0; mi < 4; mi++)
      #pragma unroll
      for (int ni = 0; ni < 4; ni++)
        #pragma unroll
        for (int c = 0; c < 2; c++)
          acc[mi][ni] = __builtin_amdgcn_mfma_f32_16x16x32_bf16(af[mi][c], bfr[ni][c], acc[mi][ni], 0, 0, 0);
    __syncthreads();
  }
  const int bx = blockIdx.x;
  if (bx < 32) {                                  // Q (bx<16) or K block
    const float scale = bx < 16 ? QSCALE : 1.0f;
    u16* outb = bx < 16 ? Qb : Kb;
    const float sgn = (n & 1) ? 1.0f : -1.0f;
    #pragma unroll
    for (int mi = 0; mi < 4; mi++)
      #pragma unroll
      for (int r = 0; r < 4; r++) {
        int row = m0 + wm + mi * 16 + g * 4 + r;
        int s = row & (SEQ - 1);
        #pragma unroll
        for (int ni = 0; ni < 4; ni++) {
          int cl = wn + ni * 16 + n;
          float val = acc[mi][ni][r];
          float par = __shfl_xor(val, 1);
          float2 cs = CS2[(size_t)s * 32 + ((cl >> 1) & 31)];
          float o = (val * cs.x + sgn * par * cs.y) * scale;
          int col = n0 + cl;
          int inst = (row >> 11) * 32 + ((col >> 6) & 31);
          outb[((size_t)inst * SEQ + s) * 64 + (col & 63)] = f2bf(o);
        }
      }
  } else {                                        // V block -> compact Vbuf
    const int vbase = (bx - 32) * 128;
    #pragma unroll
    for (int mi = 0; mi < 4; mi++)
      #pragma unroll
      for (int ni = 0; ni < 4; ni++)
        #pragma unroll
        for (int r = 0; r < 4; r++) {
          int row = m0 + wm + mi * 16 + g * 4 + r;
          Vbuf[(size_t)row * 2048 + vbase + wn + ni * 16 + n] = f2bf(acc[mi][ni][r]);
        }
  }
}

// ---------------- generic BT-GEMM (GEMM2, fp32 out) ----------------
template<int BF16OUT>
__global__ __launch_bounds__(256) void k_gemm_bt(const u16* __restrict__ A,
                                                 const u16* __restrict__ B,
                                                 void* __restrict__ Cp,
                                                 int M, int N, int K) {
  __shared__ __align__(16) u16 As[128 * 64];
  __shared__ __align__(16) u16 Bs[128 * 64];
  const int t = threadIdx.x, w = t >> 6, l = t & 63, n = l & 15, g = l >> 4;
  const int m0 = blockIdx.y * 128, n0 = blockIdx.x * 128;
  const int wm = (w >> 1) * 64, wn = (w & 1) * 64;
  f32x4 acc[4][4];
  #pragma unroll
  for (int i = 0; i < 4; i++)
    #pragma unroll
    for (int j = 0; j < 4; j++) acc[i][j] = (f32x4){0.f, 0.f, 0.f, 0.f};

  for (int kt = 0; kt < K; kt += 64) {
    #pragma unroll
    for (int p = 0; p < 4; ++p) {
      int id = p * 256 + t;
      int row = id >> 3, cc = id & 7, ccg = (cc ^ row) & 7;
      GLD_LDS16(A + (size_t)(m0 + row) * K + kt + ccg * 8, As + (size_t)(p * 256 + w * 64) * 8);
      GLD_LDS16(B + (size_t)(n0 + row) * K + kt + ccg * 8, Bs + (size_t)(p * 256 + w * 64) * 8);
    }
    __syncthreads();
    bf16x8 af[4][2], bfr[4][2];
    #pragma unroll
    for (int mi = 0; mi < 4; mi++) {
      int row = wm + mi * 16 + n;
      #pragma unroll
      for (int c = 0; c < 2; c++)
        af[mi][c] = *(const bf16x8*)(As + ((size_t)row * 8 + (((c * 4 + g) ^ row) & 7)) * 8);
    }
    #pragma unroll
    for (int ni = 0; ni < 4; ni++) {
      int row = wn + ni * 16 + n;
      #pragma unroll
      for (int c = 0; c < 2; c++)
        bfr[ni][c] = *(const bf16x8*)(Bs + ((size_t)row * 8 + (((c * 4 + g) ^ row) & 7)) * 8);
    }
    #pragma unroll
    for (int mi = 0; mi < 4; mi++)
      #pragma unroll
      for (int ni = 0; ni < 4; ni++)
        #pragma unroll
        for (int c = 0; c < 2; c++)
          acc[mi][ni] = __builtin_amdgcn_mfma_f32_16x16x32_bf16(af[mi][c], bfr[ni][c], acc[mi][ni], 0, 0, 0);
    __syncthreads();
  }
  #pragma unroll
  for (int mi = 0; mi < 4; mi++)
    #pragma unroll
    for (int ni = 0; ni < 4; ni++)
      #pragma unroll
      for (int r = 0; r < 4; r++) {
        int row = m0 + wm + mi * 16 + g * 4 + r;
        int col = n0 + wn + ni * 16 + n;
        if (BF16OUT) ((u16*)Cp)[(size_t)row * N + col] = f2bf(acc[mi][ni][r]);
        else         ((float*)Cp)[(size_t)row * N + col] = acc[mi][ni][r];
      }
}

// ---------------- V transpose: Vbuf -> Vt TILED [bh][kt32=64][128 dv][32 key]
__global__ __launch_bounds__(256) void k_vtrans(const u16* __restrict__ Vbuf,
                                                u16* __restrict__ Vt) {
  __shared__ __align__(16) u16 tile[64 * 80];   // pad to 160B stride
  int t = threadIdx.x;
  int st = blockIdx.x, dt = blockIdx.y, bh = blockIdx.z;
  int b = bh >> 4, h = bh & 15;
  #pragma unroll
  for (int p = 0; p < 2; p++) {
    int id = p * 256 + t, sr = id >> 3, cc = id & 7;
    const u16* gsrc = Vbuf + (size_t)(b * SEQ + st * 64 + sr) * 2048 + h * 128 + dt * 64 + cc * 8;
    *(uint4*)(tile + sr * 80 + cc * 8) = *(const uint4*)gsrc;
  }
  __syncthreads();
  #pragma unroll
  for (int p = 0; p < 2; p++) {
    int id = p * 256 + t, dr = id >> 3, cc = id & 7;
    union { u16 v[8]; uint4 q; } uu;
    #pragma unroll
    for (int j = 0; j < 8; j++) uu.v[j] = tile[(cc * 8 + j) * 80 + dr];
    u16* gdst = Vt + ((((size_t)bh * 64 + st * 2 + (cc >> 2)) * 128 + dt * 64 + dr) * 32) + (cc & 3) * 8;
    *(uint4*)gdst = uu.q;
  }
}

// ---------------- flash attention v8 (v7 + packed bf16 cvt) ----------------
__global__ __launch_bounds__(256, 4) void k_flash(const u16* __restrict__ Q,
                                                  const u16* __restrict__ K,
                                                  const u16* __restrict__ V,
                                                  u16* __restrict__ PA, u16* __restrict__ PB,
                                                  float* __restrict__ LA, float* __restrict__ LB) {
  __shared__ __align__(16) u16 Ks[2][32 * 64];
  __shared__ __align__(16) u16 Vs[2][128 * 32];
  __shared__ __align__(16) u16 Ps[4][32 * 32];
  const int t = threadIdx.x, w = t >> 6, l = t & 63, n = l & 15, g = l >> 4;
  const int gb = blockIdx.x;
  const int xcd = gb & 7, qq = gb >> 3, j = qq & 15, ihi = qq >> 4;
  const int inst = ihi * 8 + xcd;
  const int b = inst >> 5, rh = inst & 31, h = rh >> 1, bh = b * 16 + h;
  const u16* Qp = Q + (size_t)inst * SEQ * 64;
  const u16* Kp = K + (size_t)inst * SEQ * 64;
  const u16* Vp = V + (size_t)bh * 262144;
  u16* Pw = Ps[w];

  #pragma unroll
  for (int ch = 0; ch < 2; ch++) {
    const int tile = ch ? j : (15 - j);
    const int k0 = ch ? (2 * j + 2) : 0;
    const int k1 = ch ? (4 * j + 4) : (32 - 2 * j);
    const int rw = tile * 128 + w * 32;
    u16* Od = ch ? PB : PA;
    float* Ld = ch ? LB : LA;

    bf16x8 qf[2][2];
    #pragma unroll
    for (int q2 = 0; q2 < 2; q2++)
      #pragma unroll
      for (int c = 0; c < 2; c++)
        qf[q2][c] = *(const bf16x8*)(Qp + (size_t)(rw + q2 * 16 + n) * 64 + c * 32 + g * 8);

    f32x4 o_acc[2][8];
    #pragma unroll
    for (int q2 = 0; q2 < 2; q2++)
      #pragma unroll
      for (int nb = 0; nb < 8; nb++) o_acc[q2][nb] = (f32x4){0.f, 0.f, 0.f, 0.f};
    float lsum[2] = {0.f, 0.f};

    __syncthreads();
    {   // stage k0 -> buffer 0
      int row = t >> 3, cc = t & 7, ccg = cc ^ (row & 7);
      GLD_LDS16(Kp + (size_t)(k0 * 32 + row) * 64 + ccg * 8, Ks[0] + (size_t)w * 512);
      #pragma unroll
      for (int p = 0; p < 2; p++) {
        int id = p * 256 + t, vr = id >> 2, vc = id & 3, vcg = vc ^ (vr & 3);
        GLD_LDS16(Vp + (size_t)k0 * 4096 + vr * 32 + vcg * 8, Vs[0] + (size_t)(p * 256 + w * 64) * 8);
      }
    }

    for (int kt = k0; kt < k1; ++kt) {
      const int par = (kt - k0) & 1;
      __syncthreads();
      if (kt + 1 < k1) {
        int row = t >> 3, cc = t & 7, ccg = cc ^ (row & 7);
        GLD_LDS16(Kp + (size_t)((kt + 1) * 32 + row) * 64 + ccg * 8,
                  Ks[par ^ 1] + (size_t)w * 512);
        const u16* Vtile = Vp + (size_t)(kt + 1) * 4096;
        #pragma unroll
        for (int p = 0; p < 2; p++) {
          int id = p * 256 + t, vr = id >> 2, vc = id & 3, vcg = vc ^ (vr & 3);
          GLD_LDS16(Vtile + (size_t)vr * 32 + vcg * 8, Vs[par ^ 1] + (size_t)(p * 256 + w * 64) * 8);
        }
      }
      if (kt * 32 <= rw + 31) {
        const u16* Kc = Ks[par];
        const u16* Vc = Vs[par];
        f32x4 st[2][2];
        st[0][0] = st[0][1] = st[1][0] = st[1][1] = (f32x4){0.f, 0.f, 0.f, 0.f};
        #pragma unroll
        for (int kb2 = 0; kb2 < 2; kb2++) {
          int krow = kb2 * 16 + n;
          #pragma unroll
          for (int c = 0; c < 2; c++) {
            bf16x8 kf = *(const bf16x8*)(Kc + (size_t)krow * 64 + (((c * 4 + g) ^ (n & 7)) * 8));
            st[0][kb2] = __builtin_amdgcn_mfma_f32_16x16x32_bf16(kf, qf[0][c], st[0][kb2], 0, 0, 0);
            st[1][kb2] = __builtin_amdgcn_mfma_f32_16x16x32_bf16(kf, qf[1][c], st[1][kb2], 0, 0, 0);
          }
        }
        if (kt * 32 + 31 > rw) {
          #pragma unroll
          for (int q2 = 0; q2 < 2; q2++)
            #pragma unroll
            for (int kb2 = 0; kb2 < 2; kb2++)
              #pragma unroll
              for (int r = 0; r < 4; r++)
                if (kt * 32 + kb2 * 16 + g * 4 + r > rw + q2 * 16 + n) st[q2][kb2][r] = -1e30f;
        }
        #pragma unroll
        for (int q2 = 0; q2 < 2; q2++) {
          int Prow = q2 * 16 + n;
          #pragma unroll
          for (int kb2 = 0; kb2 < 2; kb2++) {
            float p0 = exp2f(st[q2][kb2][0]), p1 = exp2f(st[q2][kb2][1]);
            float p2 = exp2f(st[q2][kb2][2]), p3 = exp2f(st[q2][kb2][3]);
            lsum[q2] += (p0 + p1) + (p2 + p3);
            uint2 dd;
            dd.x = pk2(p0, p1);
            dd.y = pk2(p2, p3);
            *(uint2*)(Pw + (size_t)Prow * 32 + (((kb2 * 4 + g) ^ (n & 6)) * 4)) = dd;
          }
        }
        bf16x8 pf0 = *(const bf16x8*)(Pw + (size_t)n * 32 + (((2 * g) ^ (n & 6)) * 4));
        bf16x8 pf1 = *(const bf16x8*)(Pw + (size_t)(16 + n) * 32 + (((2 * g) ^ (n & 6)) * 4));
        #pragma unroll
        for (int nb = 0; nb < 8; nb++) {
          int dv = nb * 16 + n;
          bf16x8 vf = *(const bf16x8*)(Vc + (size_t)dv * 32 + ((g ^ (n & 3)) * 8));
          o_acc[0][nb] = __builtin_amdgcn_mfma_f32_16x16x32_bf16(pf0, vf, o_acc[0][nb], 0, 0, 0);
          o_acc[1][nb] = __builtin_amdgcn_mfma_f32_16x16x32_bf16(pf1, vf, o_acc[1][nb], 0, 0, 0);
        }
      }
    }
    #pragma unroll
    for (int q2 = 0; q2 < 2; q2++) {
      lsum[q2] += __shfl_xor(lsum[q2], 16);
      lsum[q2] += __shfl_xor(lsum[q2], 32);
    }
    u16* Op = Od + (size_t)inst * SEQ * 128;
    #pragma unroll
    for (int q2 = 0; q2 < 2; q2++)
      #pragma unroll
      for (int nb = 0; nb < 8; nb++)
        #pragma unroll
        for (int r = 0; r < 4; r++) {
          int qrow = rw + q2 * 16 + g * 4 + r;
          Op[(size_t)qrow * 128 + nb * 16 + n] = f2bf(o_acc[q2][nb][r]);
        }
    if (l < 16) {
      Ld[(size_t)inst * SEQ + rw + n]      = lsum[0];
      Ld[(size_t)inst * SEQ + rw + 16 + n] = lsum[1];
    }
  }
}

// ---------------- combine: lambda (in-wave) + merge split-K partials,
// attn1 - lam*attn2, RMSNorm(128), subln, (1-lambda_init) ----------------
__global__ __launch_bounds__(256) void k_combine(const u16* __restrict__ PA,
                                                 const u16* __restrict__ PB,
                                                 const float* __restrict__ LA,
                                                 const float* __restrict__ LB,
                                                 const float* __restrict__ lq1,
                                                 const float* __restrict__ lk1,
                                                 const float* __restrict__ lq2,
                                                 const float* __restrict__ lk2,
                                                 const float* __restrict__ subw,
                                                 u16* __restrict__ At) {
  const int t = threadIdx.x, w = t >> 6, l = t & 63;
  float s1 = lq1[l] * lk1[l];
  float s2 = lq2[l] * lk2[l];
  #pragma unroll
  for (int d = 1; d < 64; d <<= 1) { s1 += __shfl_xor(s1, d); s2 += __shfl_xor(s2, d); }
  const float lam = expf(s1) - expf(s2) + LAMBDA_INIT;
  const int W = blockIdx.x * 4 + w;          // (b*SEQ+s)*16 + h
  const int hh = W & 15, row = W >> 4;
  const int b = row >> 11, s = row & (SEQ - 1);
  const int e1 = b * 32 + hh * 2;
  const size_t base1 = ((size_t)e1 * SEQ + s) * 128 + 2 * l;
  const size_t base2 = base1 + (size_t)SEQ * 128;
  uint32_t u1a = *(const uint32_t*)(PA + base1);
  uint32_t u1b = *(const uint32_t*)(PB + base1);
  uint32_t u2a = *(const uint32_t*)(PA + base2);
  uint32_t u2b = *(const uint32_t*)(PB + base2);
  float inv1 = 1.0f / (LA[(size_t)e1 * SEQ + s] + LB[(size_t)e1 * SEQ + s]);
  float inv2 = 1.0f / (LA[(size_t)(e1 + 1) * SEQ + s] + LB[(size_t)(e1 + 1) * SEQ + s]);
  float o10 = (bf2f(u1a & 0xffffu) + bf2f(u1b & 0xffffu)) * inv1;
  float o11 = (bf2f(u1a >> 16) + bf2f(u1b >> 16)) * inv1;
  float o20 = (bf2f(u2a & 0xffffu) + bf2f(u2b & 0xffffu)) * inv2;
  float o21 = (bf2f(u2a >> 16) + bf2f(u2b >> 16)) * inv2;
  float a0 = o10 - lam * o20;
  float a1 = o11 - lam * o21;
  float ss = a0 * a0 + a1 * a1;
  #pragma unroll
  for (int d = 1; d < 64; d <<= 1) ss += __shfl_xor(ss, d);
  float rms = rsqrtf(ss * (1.0f / 128.0f) + EPSF);
  float k = rms * (1.0f - LAMBDA_INIT);
  *(uint32_t*)(At + (size_t)row * MDIM + hh * 128 + 2 * l) =
      pk2(a0 * subw[2 * l] * k, a1 * subw[2 * l + 1] * k);
}

// ---------------- host ----------------
extern "C" void kernel_launch(void* const* d_in, const int* in_sizes, int n_in,
                              void* d_out, int out_size, void* d_ws, size_t ws_size,
                              hipStream_t stream) {
  const float* x    = (const float*)d_in[0];
  const float* wq   = (const float*)d_in[1];
  const float* wk   = (const float*)d_in[2];
  const float* wv   = (const float*)d_in[3];
  const float* wo   = (const float*)d_in[4];
  const float* lq1  = (const float*)d_in[5];
  const float* lk1  = (const float*)d_in[6];
  const float* lq2  = (const float*)d_in[7];
  const float* lk2  = (const float*)d_in[8];
  const float* subw = (const float*)d_in[9];
  const float* rc   = (const float*)d_in[10];
  const float* rsn  = (const float*)d_in[11];

  char* ws = (char*)d_ws;
  u16*   Xbf  = (u16*)(ws + 0);            // 16.78 MB (dead after GEMM1 -> LA/LB)
  u16*   Wqkv = (u16*)(ws + 16777216);     // 25.17 MB (dead after GEMM1 -> At)
  u16*   Wob  = (u16*)(ws + 41943040);     //  8.39 MB
  float* CSb  = (float*)(ws + 50331648);   //  0.52 MB cos/sin float2 table
  u16*   Qb   = (u16*)(ws + 50855936);     // 16.78 MB
  u16*   Kb   = (u16*)(ws + 67633152);     // 16.78 MB
  u16*   Vbuf = (u16*)(ws + 84410368);     // 16.78 MB (V cols only)
  u16*   Vt   = (u16*)(ws + 101187584);    // 16.78 MB tiled [bh][kt32][dv][key]
  u16*   ObA  = (u16*)(ws + 117964800);    // 33.55 MB split-K partial A
  u16*   ObB  = (u16*)(ws + 151519232);    // 33.55 MB split-K partial B
  float* LA   = (float*)(ws + 0);          // aliases dead Xbf
  float* LB   = (float*)(ws + 524288);
  u16*   At   = Wqkv;                      // aliases dead Wqkv
  if (ws_size < 185073664) return;

  k_castall<<<24640, 256, 0, stream>>>((const float4*)x, (const float4*)wq,
                                       (const float4*)wk, (const float4*)wv,
                                       (const float4*)wo, (const float4*)rc,
                                       (const float4*)rsn,
                                       Xbf, Wqkv, Wob, (float4*)CSb);
  k_gemm_qkv<<<dim3(48, 32), 256, 0, stream>>>(Xbf, Wqkv, (const float2*)CSb,
                                               Qb, Kb, Vbuf);
  k_vtrans<<<dim3(32, 2, 32), 256, 0, stream>>>(Vbuf, Vt);
  k_flash<<<1024, 256, 0, stream>>>(Qb, Kb, Vt, ObA, ObB, LA, LB);
  k_combine<<<16384, 256, 0, stream>>>(ObA, ObB, LA, LB, lq1, lk1, lq2, lk2, subw, At);
  k_gemm_bt<0><<<dim3(16, 32), 256, 0, stream>>>(At, Wob, d_out, NROWS, MDIM, MDIM);
}